// Round 7
// baseline (9200.871 us; speedup 1.0000x reference)
//
#include <hip/hip_runtime.h>

#define TINN 512
#define FF 64
#define HHD 512
#define TOUTN 64

using v8h = __attribute__((ext_vector_type(8))) _Float16;
using v4h = __attribute__((ext_vector_type(4))) _Float16;
using v4f = __attribute__((ext_vector_type(4))) float;
using u64 = unsigned long long;

#define AGT __HIP_MEMORY_SCOPE_AGENT

// ---------------- LDS layout (bytes) ----------------
// B (weights) stored in MFMA fragment order: element (col c = nt*16+l, k) at
// (((kc*2+ks)*4+nt)*64 + quad*16 + l)*16 + j*2   [k = kc*64+ks*32+quad*8+j]
// -> every ds_read_b128 in the K-loop is base + lane*16: conflict-free.
#define WOFF 0            // max K=1024: 64 cols * 2048 B = 131072
#define GBUF_OFF 131072   // 64 x 65 f32 = 16640
#define BIAS_OFF 147712
#define WIH0_OFF 147968
#define PREV_OFF 148224
#define PART_OFF 148480   // 1024
#define PROJW_OFF 149504  // 2048
#define PROJB_OFF 151552
#define SMEM_TOTAL 151616

// ---------------- workspace layout ----------------
#define WS_BAR 0       // 4 groups x 64 slots x 64B = 16 KB (memset each launch)
#define WS_HOFF 16384  // h0[0], h0[1], h1[0], h1[1] : each 256*512*2 = 262144 B
#define HBYTES (256 * HHD * 2)

static __device__ __forceinline__ float sigm(float x) { return 1.0f / (1.0f + __expf(-x)); }
static __device__ __forceinline__ float tanh_f(float x) { return 1.0f - 2.0f / (1.0f + __expf(2.0f * x)); }

// h WRITES: agent-scope bypass stores -> land directly at the LLC coherence
// point (always fresh, tiny traffic: 2KB/block/phase). No fences emitted.
static __device__ __forceinline__ void astore8(_Float16* p, v4h v) {
  union { u64 u; v4h h; } c;
  c.h = v;
  __hip_atomic_store((u64*)p, c.u, __ATOMIC_RELAXED, AGT);
}
static __device__ __forceinline__ void astore8z(void* p) {
  __hip_atomic_store((u64*)p, 0ull, __ATOMIC_RELAXED, AGT);
}

// h READS: plain cached loads (global_load_dwordx4, L1+L2 cached, line-
// granular, XCD-shared), made coherent by ONE agent-acquire fence
// (buffer_inv) per phase in the barrier tail. Any line cached after the
// inv is post-barrier and therefore fresh (data reached LLC pre-flag).
static __device__ void groupBarrier(unsigned* slots, int r, unsigned target) {
  __builtin_amdgcn_s_waitcnt(0);   // h bypass-stores acked at LLC pre-flag
  __syncthreads();
  if (threadIdx.x == 0)
    __hip_atomic_store(&slots[(size_t)r * 16], target, __ATOMIC_RELAXED, AGT);
  if (threadIdx.x < 64) {
    while (__hip_atomic_load(&slots[(size_t)threadIdx.x * 16],
                             __ATOMIC_RELAXED, AGT) < target)
      __builtin_amdgcn_s_sleep(1);
  }
  __syncthreads();
#if __has_builtin(__builtin_amdgcn_fence)
  __builtin_amdgcn_fence(__ATOMIC_ACQUIRE, "agent");   // buffer_inv
#else
  __threadfence();
#endif
#if __has_builtin(__builtin_amdgcn_sched_barrier)
  __builtin_amdgcn_sched_barrier(0);  // keep next phase's loads after the inv
#endif
}

// Weight slice (64 gate-cols x K) fp32->fp16 into LDS, fragment order.
static __device__ __attribute__((noinline)) void loadWeights(
    int tid, int hc0, const float* W1, int ld1, int K1,
    const float* W2, int K) {
  extern __shared__ char smem[];
  int c = tid >> 2, sub = tid & 3;
  int nt = c >> 4, l = c & 15;
  int n = nt * HHD + hc0 + l;
  int Kq = K >> 2;
  for (int k = sub * Kq; k < (sub + 1) * Kq; ++k) {
    float v;
    if (k < K1) v = W1[(size_t)n * ld1 + k];
    else        v = W2[(size_t)n * HHD + (k - K1)];
    int kc = k >> 6, ks = (k >> 5) & 1, quad = (k >> 3) & 3, j = k & 7;
    int off = (((kc * 2 + ks) * 4 + nt) * 64 + quad * 16 + l) * 16 + j * 2;
    *(_Float16*)(smem + WOFF + off) = (_Float16)v;
  }
}

// One LSTM cell step for this block's (m0 batch rows, hc0 h-cols) 64x16 tile.
// Waves partition M (wave w = rows w*16..w*16+15): A read exactly once per
// block, cached global->reg; B from LDS conflict-free fragment layout.
template <int NC>
static __device__ __attribute__((noinline)) void gemmStep(
    int tid, int m0, int hc0, const float* xstep,
    const _Float16* src1, const _Float16* src2,
    int rank1, _Float16* hout, float* creg) {
  extern __shared__ char smem[];
  int lane = tid & 63, wave = tid >> 6;
  int l15 = lane & 15, quad = lane >> 4;

  v4f zero4 = {0.f, 0.f, 0.f, 0.f};
  v4f acc0 = zero4, acc1 = zero4, acc2 = zero4, acc3 = zero4;

  int ra = m0 + wave * 16 + l15;           // this lane's A row
  const char* wb = smem + WOFF + (size_t)lane * 16;

#pragma unroll
  for (int ci = 0; ci < NC; ++ci) {
    v8h ak0, ak1;
    if (xstep != nullptr && ci == 0) {
      // chunk 0 of encoder layer0: fp32 x cols 0..63 (read-only, cached)
      const float* xr = xstep + (size_t)ra * (TINN * FF) + quad * 8;
      v4f f00 = *(const v4f*)(xr);
      v4f f01 = *(const v4f*)(xr + 4);
      v4f f10 = *(const v4f*)(xr + 32);
      v4f f11 = *(const v4f*)(xr + 36);
#pragma unroll
      for (int e = 0; e < 4; ++e) {
        ak0[e] = (_Float16)f00[e]; ak0[4 + e] = (_Float16)f01[e];
        ak1[e] = (_Float16)f10[e]; ak1[4 + e] = (_Float16)f11[e];
      }
    } else {
      int cj = (xstep != nullptr) ? ci - 1 : ci;
      bool inS2 = (src2 != nullptr) && (cj >= 8);
      const _Float16* pr = (inS2 ? src2 : src1) + (size_t)ra * HHD +
                           (inS2 ? cj - 8 : cj) * 64 + quad * 8;
      ak0 = *(const v8h*)(pr);        // cached; coherence via phase inv
      ak1 = *(const v8h*)(pr + 32);
    }
    const char* bb = wb + (size_t)ci * 8192;
#pragma unroll
    for (int ks = 0; ks < 2; ++ks) {
      v8h a = ks ? ak1 : ak0;
      v8h b0 = *(const v8h*)(bb + (ks * 4 + 0) * 1024);
      v8h b1 = *(const v8h*)(bb + (ks * 4 + 1) * 1024);
      v8h b2 = *(const v8h*)(bb + (ks * 4 + 2) * 1024);
      v8h b3 = *(const v8h*)(bb + (ks * 4 + 3) * 1024);
      acc0 = __builtin_amdgcn_mfma_f32_16x16x32_f16(a, b0, acc0, 0, 0, 0);
      acc1 = __builtin_amdgcn_mfma_f32_16x16x32_f16(a, b1, acc1, 0, 0, 0);
      acc2 = __builtin_amdgcn_mfma_f32_16x16x32_f16(a, b2, acc2, 0, 0, 0);
      acc3 = __builtin_amdgcn_mfma_f32_16x16x32_f16(a, b3, acc3, 0, 0, 0);
    }
  }

  // gates -> LDS gbuf (free since prior phase's reads completed pre-barrier)
  float* gb = (float*)(smem + GBUF_OFF);
#pragma unroll
  for (int r = 0; r < 4; ++r) {
    int row = wave * 16 + quad * 4 + r;
    gb[row * 65 + l15] = acc0[r];
    gb[row * 65 + 16 + l15] = acc1[r];
    gb[row * 65 + 32 + l15] = acc2[r];
    gb[row * 65 + 48 + l15] = acc3[r];
  }
  __syncthreads();

  float* bias = (float*)(smem + BIAS_OFF);
  float* wih0 = (float*)(smem + WIH0_OFF);
  float* prevl = (float*)(smem + PREV_OFF);
  int m = tid >> 2, jb = (tid & 3) * 4;
  float pv = rank1 ? prevl[m] : 0.0f;
  v4h hh;
#pragma unroll
  for (int i = 0; i < 4; ++i) {
    int j = jb + i;
    float gi = gb[m * 65 + j] + bias[j];
    float gf = gb[m * 65 + 16 + j] + bias[16 + j];
    float gg = gb[m * 65 + 32 + j] + bias[32 + j];
    float go = gb[m * 65 + 48 + j] + bias[48 + j];
    if (rank1) {
      gi += pv * wih0[j]; gf += pv * wih0[16 + j];
      gg += pv * wih0[32 + j]; go += pv * wih0[48 + j];
    }
    float c = sigm(gf) * creg[i] + sigm(gi) * tanh_f(gg);
    float h = sigm(go) * tanh_f(c);
    creg[i] = c;
    hh[i] = (_Float16)h;
  }
  astore8(hout + (size_t)(m0 + m) * HHD + hc0 + jb, hh);
  // caller's groupBarrier provides the sync before gbuf is reused
}

__global__ void __launch_bounds__(256, 1)
seq2seq_kernel(const float* x,
               const float* e0wi, const float* e0wh, const float* e0bi, const float* e0bh,
               const float* e1wi, const float* e1wh, const float* e1bi, const float* e1bh,
               const float* d0wi, const float* d0wh, const float* d0bi, const float* d0bh,
               const float* d1wi, const float* d1wh, const float* d1bi, const float* d1bh,
               const float* pw, const float* pb,
               float* out, char* ws) {
  extern __shared__ char smem[];
  int tid = threadIdx.x, bid = blockIdx.x;
  int group = bid >> 6;       // 4 groups x 64 blocks; group owns batch rows [64g, 64g+64)
  int r = bid & 63;
  bool isL1 = (r >= 32);
  int hcTile = r & 31;
  int hc0 = hcTile * 16;
  int m0 = group * 64;
  unsigned* slots = (unsigned*)(ws + WS_BAR) + (size_t)group * 1024;  // 64 slots x 64B
  unsigned barGen = 0;

  _Float16* h0b[2]; _Float16* h1b[2];
  h0b[0] = (_Float16*)(ws + WS_HOFF);
  h0b[1] = (_Float16*)(ws + WS_HOFF + HBYTES);
  h1b[0] = (_Float16*)(ws + WS_HOFF + 2 * HBYTES);
  h1b[1] = (_Float16*)(ws + WS_HOFF + 3 * HBYTES);

  float creg[4];
  creg[0] = 0.f; creg[1] = 0.f; creg[2] = 0.f; creg[3] = 0.f;

  // zero this group's slice of all four h buffers (LLC-visible stores)
  {
    int q = r >> 4;     // which buffer
    int rb = r & 15;    // 4-row block within group's 64 rows
    char* zp = ws + WS_HOFF + (size_t)q * HBYTES +
               ((size_t)(m0 + rb * 4) * HHD) * 2 + (size_t)tid * 16;
    astore8z(zp);
    astore8z(zp + 8);
  }

  // encoder-role weights + biases into LDS
  if (!isL1) {
    loadWeights(tid, hc0, e0wi, 64, 64, e0wh, 576);
    if (tid < 64) {
      int n = (tid >> 4) * HHD + hc0 + (tid & 15);
      ((float*)(smem + BIAS_OFF))[tid] = e0bi[n] + e0bh[n];
    }
  } else {
    loadWeights(tid, hc0, e1wi, 512, 512, e1wh, 1024);
    if (tid < 64) {
      int n = (tid >> 4) * HHD + hc0 + (tid & 15);
      ((float*)(smem + BIAS_OFF))[tid] = e1bi[n] + e1bh[n];
    }
  }
  barGen++; groupBarrier(slots, r, barGen);

  // -------- encoder: phase p runs enc0 step p and enc1 step p-1 --------
  for (int p = 0; p <= TINN; ++p) {
    if (!isL1) {
      if (p < TINN)
        gemmStep<9>(tid, m0, hc0, x + (size_t)p * FF, h0b[(p & 1) ^ 1], nullptr,
                    0, h0b[p & 1], creg);
    } else {
      if (p >= 1) {
        int s = p - 1;
        gemmStep<16>(tid, m0, hc0, nullptr, h0b[s & 1], h1b[(s & 1) ^ 1],
                     0, h1b[s & 1], creg);
      }
    }
    barGen++; groupBarrier(slots, r, barGen);
  }

  // -------- switch to decoder-role weights (c state stays in creg) --------
  if (!isL1) {
    loadWeights(tid, hc0, d0wh, 512, 512, nullptr, 512);
    if (tid < 64) {
      int n = (tid >> 4) * HHD + hc0 + (tid & 15);
      ((float*)(smem + BIAS_OFF))[tid] = d0bi[n] + d0bh[n];
      ((float*)(smem + WIH0_OFF))[tid] = d0wi[n];
    }
    for (int k = tid; k < 512; k += 256) ((float*)(smem + PROJW_OFF))[k] = pw[k];
    if (tid == 0) ((float*)(smem + PROJB_OFF))[0] = pb[0];
  } else {
    loadWeights(tid, hc0, d1wi, 512, 512, d1wh, 1024);
    if (tid < 64) {
      int n = (tid >> 4) * HHD + hc0 + (tid & 15);
      ((float*)(smem + BIAS_OFF))[tid] = d1bi[n] + d1bh[n];
    }
  }
  __syncthreads();
  barGen++; groupBarrier(slots, r, barGen);

  // -------- decoder: 2 phases per step (prev->h0 then h0->h1) --------
  for (int t = 0; t <= TOUTN; ++t) {
    if (!isL1) {
      float* prevl = (float*)(smem + PREV_OFF);
      if (t == 0) {
        if (tid < 64)
          prevl[tid] = x[(size_t)(m0 + tid) * (TINN * FF) + 511 * 64 + 63];
      } else {
        // prev(t) = h1(t-1) . projW + proj_b  (fp32 VALU, 4 threads per row)
        float* part = (float*)(smem + PART_OFF);
        float* pjw = (float*)(smem + PROJW_OFF);
        const _Float16* hrow = h1b[(t - 1) & 1] +
                               (size_t)(m0 + (tid >> 2)) * HHD + (tid & 3) * 128;
        float s = 0.f;
        for (int k8 = 0; k8 < 16; ++k8) {
          v8h hv = *(const v8h*)(hrow + k8 * 8);
          const float* w = pjw + (tid & 3) * 128 + k8 * 8;
#pragma unroll
          for (int e = 0; e < 8; ++e) s += (float)hv[e] * w[e];
        }
        part[tid] = s;
        __syncthreads();
        if (tid < 64) {
          float p4 = part[tid * 4] + part[tid * 4 + 1] + part[tid * 4 + 2] +
                     part[tid * 4 + 3] + ((float*)(smem + PROJB_OFF))[0];
          prevl[tid] = p4;
          if (hcTile == 0) out[(size_t)(m0 + tid) * TOUTN + (t - 1)] = p4;
        }
      }
      __syncthreads();
      if (t < TOUTN)
        gemmStep<8>(tid, m0, hc0, nullptr, h0b[(t & 1) ^ 1], nullptr,
                    1, h0b[t & 1], creg);
    }
    barGen++; groupBarrier(slots, r, barGen);
    if (isL1 && t < TOUTN)
      gemmStep<16>(tid, m0, hc0, nullptr, h0b[t & 1], h1b[(t & 1) ^ 1],
                   0, h1b[t & 1], creg);
    barGen++; groupBarrier(slots, r, barGen);
  }
}

extern "C" void kernel_launch(void* const* d_in, const int* in_sizes, int n_in,
                              void* d_out, int out_size, void* d_ws, size_t ws_size,
                              hipStream_t stream) {
  const float* x = (const float*)d_in[0];
  const float* e0wi = (const float*)d_in[2];
  const float* e0wh = (const float*)d_in[3];
  const float* e0bi = (const float*)d_in[4];
  const float* e0bh = (const float*)d_in[5];
  const float* e1wi = (const float*)d_in[6];
  const float* e1wh = (const float*)d_in[7];
  const float* e1bi = (const float*)d_in[8];
  const float* e1bh = (const float*)d_in[9];
  const float* d0wi = (const float*)d_in[10];
  const float* d0wh = (const float*)d_in[11];
  const float* d0bi = (const float*)d_in[12];
  const float* d0bh = (const float*)d_in[13];
  const float* d1wi = (const float*)d_in[14];
  const float* d1wh = (const float*)d_in[15];
  const float* d1bi = (const float*)d_in[16];
  const float* d1bh = (const float*)d_in[17];
  const float* pw = (const float*)d_in[18];
  const float* pb = (const float*)d_in[19];

  (void)hipFuncSetAttribute((const void*)seq2seq_kernel,
                            hipFuncAttributeMaxDynamicSharedMemorySize, SMEM_TOTAL);
  (void)hipMemsetAsync(d_ws, 0, 16384, stream);  // barrier slots (4 groups x 64)
  seq2seq_kernel<<<dim3(256), dim3(256), SMEM_TOTAL, stream>>>(
      x, e0wi, e0wh, e0bi, e0bh, e1wi, e1wh, e1bi, e1bh,
      d0wi, d0wh, d0bi, d0bh, d1wi, d1wh, d1bi, d1bh,
      pw, pb, (float*)d_out, (char*)d_ws);
}

// Round 8
// 6948.270 us; speedup vs baseline: 1.3242x; 1.3242x over previous
//
#include <hip/hip_runtime.h>

#define TINN 512
#define FF 64
#define HHD 512
#define TOUTN 64

using v8h = __attribute__((ext_vector_type(8))) _Float16;
using v4h = __attribute__((ext_vector_type(4))) _Float16;
using v4f = __attribute__((ext_vector_type(4))) float;
using u64 = unsigned long long;

#define AGT __HIP_MEMORY_SCOPE_AGENT

// ---------------- LDS layout (bytes) ----------------
// B (weights) in MFMA fragment order -> conflict-free ds_read_b128.
#define WOFF 0            // max K=1024: 64 cols * 2048 B = 131072
#define GBUF_OFF 131072   // 64 x 65 f32 = 16640
#define BIAS_OFF 147712
#define WIH0_OFF 147968
#define PREV_OFF 148224
#define PART_OFF 148480   // 1024
#define PROJW_OFF 149504  // 2048
#define PROJB_OFF 151552
#define SMEM_TOTAL 151616

// ---------------- workspace layout ----------------
// Slots: per group 64 slots x 64B. Slot n (n<32) = enc0/dec0 block n's
// progress; slot 32+n = enc1/dec1 block n. Value = 1 + (1 + last completed
// global step) ; 1 after init. Producer-consumer waits replace the full
// group barrier: enc0@p waits L0>=p+1, L1>=p-2 (h0 depth-4 reuse);
// enc1@s waits L0>=s+2, L1>=s+1 (h1 depth-2). Decoder continues u=512+t.
#define WS_BAR 0
#define WS_HOFF 16384
#define HBYTES (256 * HHD * 2)
// h0: 4 buffers at WS_HOFF; h1: 2 buffers after (total 1.5 MB + slots)

static __device__ __forceinline__ float sigm(float x) { return 1.0f / (1.0f + __expf(-x)); }
static __device__ __forceinline__ float tanh_f(float x) { return 1.0f - 2.0f / (1.0f + __expf(2.0f * x)); }

// Cross-block h traffic: relaxed agent-scope atomics = cache-bypass ops
// serviced at the LLC coherence point. No wbl2/inv fences ever emitted;
// read-only data (x, weights) stays cached across all phases.
static __device__ __forceinline__ v8h aload16(const _Float16* p) {
  union { u64 u[2]; v8h h; } c;
  const u64* q = (const u64*)p;
  c.u[0] = __hip_atomic_load(q, __ATOMIC_RELAXED, AGT);
  c.u[1] = __hip_atomic_load(q + 1, __ATOMIC_RELAXED, AGT);
  return c.h;
}
static __device__ __forceinline__ void astore8(_Float16* p, v4h v) {
  union { u64 u; v4h h; } c;
  c.h = v;
  __hip_atomic_store((u64*)p, c.u, __ATOMIC_RELAXED, AGT);
}
static __device__ __forceinline__ void astore8z(void* p) {
  __hip_atomic_store((u64*)p, 0ull, __ATOMIC_RELAXED, AGT);
}

// Signal: drain own vmem (h stores acked at LLC) then publish progress.
static __device__ __forceinline__ void signalDone(unsigned* slots, int mySlot, unsigned val) {
  __builtin_amdgcn_s_waitcnt(0);
  __syncthreads();
  if (threadIdx.x == 0)
    __hip_atomic_store(&slots[(size_t)mySlot * 16], val, __ATOMIC_RELAXED, AGT);
}

// Wait: lanes 0-31 poll the 32 role-0 slots against t0; lanes 32-63 poll
// role-1 slots against t1. Contention-free (pure loads), exec-masked.
static __device__ __forceinline__ void waitFor(unsigned* slots, int t0, int t1) {
  int tid = threadIdx.x;
  if (tid < 64) {
    int tgt = (tid < 32) ? t0 : t1;
    if (tgt > 0) {
      while ((int)__hip_atomic_load(&slots[(size_t)tid * 16],
                                    __ATOMIC_RELAXED, AGT) < tgt)
        __builtin_amdgcn_s_sleep(1);
    }
  }
  __syncthreads();
#if __has_builtin(__builtin_amdgcn_sched_barrier)
  __builtin_amdgcn_sched_barrier(0);  // keep phase loads after the wait
#endif
}

// Weight slice (64 gate-cols x K) fp32->fp16 into LDS, fragment order.
static __device__ __attribute__((noinline)) void loadWeights(
    int tid, int hc0, const float* W1, int ld1, int K1,
    const float* W2, int K) {
  extern __shared__ char smem[];
  int c = tid >> 2, sub = tid & 3;
  int nt = c >> 4, l = c & 15;
  int n = nt * HHD + hc0 + l;
  int Kq = K >> 2;
  for (int k = sub * Kq; k < (sub + 1) * Kq; ++k) {
    float v;
    if (k < K1) v = W1[(size_t)n * ld1 + k];
    else        v = W2[(size_t)n * HHD + (k - K1)];
    int kc = k >> 6, ks = (k >> 5) & 1, quad = (k >> 3) & 3, j = k & 7;
    int off = (((kc * 2 + ks) * 4 + nt) * 64 + quad * 16 + l) * 16 + j * 2;
    *(_Float16*)(smem + WOFF + off) = (_Float16)v;
  }
}

// One LSTM cell step for this block's (m0 batch rows, hc0 h-cols) 64x16 tile.
// Waves partition M; A direct global->reg (16B bypass); B LDS conflict-free.
template <int NC>
static __device__ __attribute__((noinline)) void gemmStep(
    int tid, int m0, int hc0, const float* xstep,
    const _Float16* src1, const _Float16* src2,
    int rank1, _Float16* hout, float* creg) {
  extern __shared__ char smem[];
  int lane = tid & 63, wave = tid >> 6;
  int l15 = lane & 15, quad = lane >> 4;

  v4f zero4 = {0.f, 0.f, 0.f, 0.f};
  v4f acc0 = zero4, acc1 = zero4, acc2 = zero4, acc3 = zero4;

  int ra = m0 + wave * 16 + l15;           // this lane's A row
  const char* wb = smem + WOFF + (size_t)lane * 16;

#pragma unroll
  for (int ci = 0; ci < NC; ++ci) {
    v8h ak0, ak1;
    if (xstep != nullptr && ci == 0) {
      // encoder layer0 chunk 0: fp32 x cols 0..63 (read-only, cached)
      const float* xr = xstep + (size_t)ra * (TINN * FF) + quad * 8;
      v4f f00 = *(const v4f*)(xr);
      v4f f01 = *(const v4f*)(xr + 4);
      v4f f10 = *(const v4f*)(xr + 32);
      v4f f11 = *(const v4f*)(xr + 36);
#pragma unroll
      for (int e = 0; e < 4; ++e) {
        ak0[e] = (_Float16)f00[e]; ak0[4 + e] = (_Float16)f01[e];
        ak1[e] = (_Float16)f10[e]; ak1[4 + e] = (_Float16)f11[e];
      }
    } else {
      int cj = (xstep != nullptr) ? ci - 1 : ci;
      bool inS2 = (src2 != nullptr) && (cj >= 8);
      const _Float16* pr = (inS2 ? src2 : src1) + (size_t)ra * HHD +
                           (inS2 ? cj - 8 : cj) * 64 + quad * 8;
      ak0 = aload16(pr);
      ak1 = aload16(pr + 32);
    }
    const char* bb = wb + (size_t)ci * 8192;
#pragma unroll
    for (int ks = 0; ks < 2; ++ks) {
      v8h a = ks ? ak1 : ak0;
      v8h b0 = *(const v8h*)(bb + (ks * 4 + 0) * 1024);
      v8h b1 = *(const v8h*)(bb + (ks * 4 + 1) * 1024);
      v8h b2 = *(const v8h*)(bb + (ks * 4 + 2) * 1024);
      v8h b3 = *(const v8h*)(bb + (ks * 4 + 3) * 1024);
      acc0 = __builtin_amdgcn_mfma_f32_16x16x32_f16(a, b0, acc0, 0, 0, 0);
      acc1 = __builtin_amdgcn_mfma_f32_16x16x32_f16(a, b1, acc1, 0, 0, 0);
      acc2 = __builtin_amdgcn_mfma_f32_16x16x32_f16(a, b2, acc2, 0, 0, 0);
      acc3 = __builtin_amdgcn_mfma_f32_16x16x32_f16(a, b3, acc3, 0, 0, 0);
    }
  }

  // gates -> LDS gbuf
  float* gb = (float*)(smem + GBUF_OFF);
#pragma unroll
  for (int r = 0; r < 4; ++r) {
    int row = wave * 16 + quad * 4 + r;
    gb[row * 65 + l15] = acc0[r];
    gb[row * 65 + 16 + l15] = acc1[r];
    gb[row * 65 + 32 + l15] = acc2[r];
    gb[row * 65 + 48 + l15] = acc3[r];
  }
  __syncthreads();

  float* bias = (float*)(smem + BIAS_OFF);
  float* wih0 = (float*)(smem + WIH0_OFF);
  float* prevl = (float*)(smem + PREV_OFF);
  int m = tid >> 2, jb = (tid & 3) * 4;
  float pv = rank1 ? prevl[m] : 0.0f;
  v4h hh;
#pragma unroll
  for (int i = 0; i < 4; ++i) {
    int j = jb + i;
    float gi = gb[m * 65 + j] + bias[j];
    float gf = gb[m * 65 + 16 + j] + bias[16 + j];
    float gg = gb[m * 65 + 32 + j] + bias[32 + j];
    float go = gb[m * 65 + 48 + j] + bias[48 + j];
    if (rank1) {
      gi += pv * wih0[j]; gf += pv * wih0[16 + j];
      gg += pv * wih0[32 + j]; go += pv * wih0[48 + j];
    }
    float c = sigm(gf) * creg[i] + sigm(gi) * tanh_f(gg);
    float h = sigm(go) * tanh_f(c);
    creg[i] = c;
    hh[i] = (_Float16)h;
  }
  astore8(hout + (size_t)(m0 + m) * HHD + hc0 + jb, hh);
  // caller's signalDone drains these stores before publishing progress
}

__global__ void __launch_bounds__(256, 1)
seq2seq_kernel(const float* x,
               const float* e0wi, const float* e0wh, const float* e0bi, const float* e0bh,
               const float* e1wi, const float* e1wh, const float* e1bi, const float* e1bh,
               const float* d0wi, const float* d0wh, const float* d0bi, const float* d0bh,
               const float* d1wi, const float* d1wh, const float* d1bi, const float* d1bh,
               const float* pw, const float* pb,
               float* out, char* ws) {
  extern __shared__ char smem[];
  int tid = threadIdx.x, bid = blockIdx.x;
  int group = bid >> 6;       // 4 groups x 64 blocks; group owns rows [64g, 64g+64)
  int r = bid & 63;
  bool isL1 = (r >= 32);
  int hcTile = r & 31;
  int hc0 = hcTile * 16;
  int m0 = group * 64;
  unsigned* slots = (unsigned*)(ws + WS_BAR) + (size_t)group * 1024;  // 64 x 64B
  int mySlot = isL1 ? 32 + hcTile : hcTile;

  _Float16* h0b[4]; _Float16* h1b[2];
  h0b[0] = (_Float16*)(ws + WS_HOFF);
  h0b[1] = (_Float16*)(ws + WS_HOFF + 1 * HBYTES);
  h0b[2] = (_Float16*)(ws + WS_HOFF + 2 * HBYTES);
  h0b[3] = (_Float16*)(ws + WS_HOFF + 3 * HBYTES);
  h1b[0] = (_Float16*)(ws + WS_HOFF + 4 * HBYTES);
  h1b[1] = (_Float16*)(ws + WS_HOFF + 5 * HBYTES);

  float creg[4];
  creg[0] = 0.f; creg[1] = 0.f; creg[2] = 0.f; creg[3] = 0.f;

  // zero only the buffers read as "step -1": h0[3] and h1[1], group slice.
  // 64 blocks x 256 threads x 8B = 128KB = 2 x 64KB slices.
  {
    int t16 = r * 256 + tid;            // 0..16383
    char* base = (t16 < 8192) ? (char*)h0b[3] : (char*)h1b[1];
    int idx = t16 & 8191;
    astore8z(base + (size_t)m0 * HHD * 2 + (size_t)idx * 8);
  }

  // encoder-role weights + biases into LDS
  if (!isL1) {
    loadWeights(tid, hc0, e0wi, 64, 64, e0wh, 576);
    if (tid < 64) {
      int n = (tid >> 4) * HHD + hc0 + (tid & 15);
      ((float*)(smem + BIAS_OFF))[tid] = e0bi[n] + e0bh[n];
    }
  } else {
    loadWeights(tid, hc0, e1wi, 512, 512, e1wh, 1024);
    if (tid < 64) {
      int n = (tid >> 4) * HHD + hc0 + (tid & 15);
      ((float*)(smem + BIAS_OFF))[tid] = e1bi[n] + e1bh[n];
    }
  }
  signalDone(slots, mySlot, 1);   // init done (zeros at LLC, weights in LDS)

  if (!isL1) {
    // ---------------- encoder layer 0 ----------------
    for (int p = 0; p < TINN; ++p) {
      waitFor(slots, p + 1, p - 2);   // h0(p-1) written; enc1 done p-4
      gemmStep<9>(tid, m0, hc0, x + (size_t)p * FF, h0b[(p + 3) & 3], nullptr,
                  0, h0b[p & 3], creg);
      signalDone(slots, mySlot, p + 2);
    }
    // ---------------- switch to decoder layer 0 ----------------
    loadWeights(tid, hc0, d0wh, 512, 512, nullptr, 512);
    if (tid < 64) {
      int n = (tid >> 4) * HHD + hc0 + (tid & 15);
      ((float*)(smem + BIAS_OFF))[tid] = d0bi[n] + d0bh[n];
      ((float*)(smem + WIH0_OFF))[tid] = d0wi[n];
    }
    for (int k = tid; k < 512; k += 256) ((float*)(smem + PROJW_OFF))[k] = pw[k];
    if (tid == 0) ((float*)(smem + PROJB_OFF))[0] = pb[0];
    for (int t = 0; t <= TOUTN; ++t) {
      int u = TINN + t;
      waitFor(slots, u + 1, u + 1);   // d0 done t-1; d1 done t-1 (h1(t-1) ready)
      float* prevl = (float*)(smem + PREV_OFF);
      if (t == 0) {
        if (tid < 64)
          prevl[tid] = x[(size_t)(m0 + tid) * (TINN * FF) + 511 * 64 + 63];
      } else {
        float* part = (float*)(smem + PART_OFF);
        float* pjw = (float*)(smem + PROJW_OFF);
        const _Float16* hrow = h1b[(u + 1) & 1] +
                               (size_t)(m0 + (tid >> 2)) * HHD + (tid & 3) * 128;
        float s = 0.f;
        for (int k8 = 0; k8 < 16; ++k8) {
          v8h hv = aload16(hrow + k8 * 8);
          const float* w = pjw + (tid & 3) * 128 + k8 * 8;
#pragma unroll
          for (int e = 0; e < 8; ++e) s += (float)hv[e] * w[e];
        }
        part[tid] = s;
        __syncthreads();
        if (tid < 64) {
          float p4 = part[tid * 4] + part[tid * 4 + 1] + part[tid * 4 + 2] +
                     part[tid * 4 + 3] + ((float*)(smem + PROJB_OFF))[0];
          prevl[tid] = p4;
          if (hcTile == 0) out[(size_t)(m0 + tid) * TOUTN + (t - 1)] = p4;
        }
      }
      __syncthreads();
      if (t < TOUTN) {
        gemmStep<8>(tid, m0, hc0, nullptr, h0b[(u + 3) & 3], nullptr,
                    1, h0b[u & 3], creg);
        signalDone(slots, mySlot, u + 2);
      }
    }
  } else {
    // ---------------- encoder layer 1 ----------------
    for (int s = 0; s < TINN; ++s) {
      waitFor(slots, s + 2, s + 1);   // enc0 done s; enc1 done s-1
      gemmStep<16>(tid, m0, hc0, nullptr, h0b[s & 3], h1b[(s + 1) & 1],
                   0, h1b[s & 1], creg);
      signalDone(slots, mySlot, s + 2);
    }
    // ---------------- switch to decoder layer 1 ----------------
    loadWeights(tid, hc0, d1wi, 512, 512, d1wh, 1024);
    if (tid < 64) {
      int n = (tid >> 4) * HHD + hc0 + (tid & 15);
      ((float*)(smem + BIAS_OFF))[tid] = d1bi[n] + d1bh[n];
    }
    for (int t = 0; t < TOUTN; ++t) {
      int u = TINN + t;
      waitFor(slots, u + 2, u + 1);   // d0 done t; d1 done t-1
      gemmStep<16>(tid, m0, hc0, nullptr, h0b[u & 3], h1b[(u + 1) & 1],
                   0, h1b[u & 1], creg);
      signalDone(slots, mySlot, u + 2);
    }
  }
}

extern "C" void kernel_launch(void* const* d_in, const int* in_sizes, int n_in,
                              void* d_out, int out_size, void* d_ws, size_t ws_size,
                              hipStream_t stream) {
  const float* x = (const float*)d_in[0];
  const float* e0wi = (const float*)d_in[2];
  const float* e0wh = (const float*)d_in[3];
  const float* e0bi = (const float*)d_in[4];
  const float* e0bh = (const float*)d_in[5];
  const float* e1wi = (const float*)d_in[6];
  const float* e1wh = (const float*)d_in[7];
  const float* e1bi = (const float*)d_in[8];
  const float* e1bh = (const float*)d_in[9];
  const float* d0wi = (const float*)d_in[10];
  const float* d0wh = (const float*)d_in[11];
  const float* d0bi = (const float*)d_in[12];
  const float* d0bh = (const float*)d_in[13];
  const float* d1wi = (const float*)d_in[14];
  const float* d1wh = (const float*)d_in[15];
  const float* d1bi = (const float*)d_in[16];
  const float* d1bh = (const float*)d_in[17];
  const float* pw = (const float*)d_in[18];
  const float* pb = (const float*)d_in[19];

  (void)hipFuncSetAttribute((const void*)seq2seq_kernel,
                            hipFuncAttributeMaxDynamicSharedMemorySize, SMEM_TOTAL);
  (void)hipMemsetAsync(d_ws, 0, 16384, stream);  // progress slots (4 groups x 64)
  seq2seq_kernel<<<dim3(256), dim3(256), SMEM_TOTAL, stream>>>(
      x, e0wi, e0wh, e0bi, e0bh, e1wi, e1wh, e1bi, e1bh,
      d0wi, d0wh, d0bi, d0bh, d1wi, d1wh, d1bi, d1bh,
      pw, pb, (float*)d_out, (char*)d_ws);
}

// Round 9
// 4736.340 us; speedup vs baseline: 1.9426x; 1.4670x over previous
//
#include <hip/hip_runtime.h>

#define TINN 512
#define FF 64
#define HHD 512
#define TOUTN 64

using v8h = __attribute__((ext_vector_type(8))) _Float16;
using v4h = __attribute__((ext_vector_type(4))) _Float16;
using v4f = __attribute__((ext_vector_type(4))) float;
using u32x4 = __attribute__((ext_vector_type(4))) unsigned int;
using u64 = unsigned long long;

#define AGT __HIP_MEMORY_SCOPE_AGENT

// ---------------- LDS layout (bytes) ----------------
#define WOFF 0            // weights, MFMA fragment order (max 128KB)
#define GBUF_OFF 131072   // 64 x 65 f32 = 16640
#define BIAS_OFF 147712
#define WIH0_OFF 147968
#define PREV_OFF 148224
#define PART_OFF 148480
#define PROJW_OFF 149504
#define PROJB_OFF 151552
#define SMEM_TOTAL 151616

// ---------------- workspace layout ----------------
// Progress slots (r8 protocol), then 6 h buffers, then fp16 swizzled x.
// h/x SWIZZLED LAYOUT (per 256row x 512col buffer; per-t for xs with kc=0):
//   off(m,c) = ((rt*KC + kc)*2 + ks)*1024 + (quad*16 + l15)*16 + j*2
//   rt=m>>4, l15=m&15, kc=c>>6, ks=(c>>5)&1, quad=(c>>3)&3, j=c&7
// -> a wave's A-fragment load is base + lane*16: 1KB fully coalesced.
#define WS_BAR 0
#define WS_HOFF 16384
#define HBYTES (256 * HHD * 2)
#define WS_XS (WS_HOFF + 6 * HBYTES)
#define XS_TBYTES 32768              // per-t: 16rt x 2ks x 1024
#define WS_NEED (WS_XS + (size_t)TINN * XS_TBYTES)

static __device__ __forceinline__ float sigm(float x) { return 1.0f / (1.0f + __expf(-x)); }
static __device__ __forceinline__ float tanh_f(float x) { return 1.0f - 2.0f / (1.0f + __expf(2.0f * x)); }

// Cross-block h traffic: cache-bypass ops serviced at the LLC coherence
// point. No wbl2/inv fences emitted; read-only data stays cached.
static __device__ __forceinline__ v8h aload16(const _Float16* p) {
  union { u64 u[2]; v8h h; } c;
  const u64* q = (const u64*)p;
  c.u[0] = __hip_atomic_load(q, __ATOMIC_RELAXED, AGT);
  c.u[1] = __hip_atomic_load(q + 1, __ATOMIC_RELAXED, AGT);
  return c.h;
}
static __device__ __forceinline__ void astore8(_Float16* p, v4h v) {
  union { u64 u; v4h h; } c;
  c.h = v;
  __hip_atomic_store((u64*)p, c.u, __ATOMIC_RELAXED, AGT);
}
static __device__ __forceinline__ void astore8z(void* p) {
  __hip_atomic_store((u64*)p, 0ull, __ATOMIC_RELAXED, AGT);
}

#if __has_builtin(__builtin_amdgcn_raw_ptr_buffer_load_b128) && \
    __has_builtin(__builtin_amdgcn_make_buffer_rsrc)
#define HAVE_BUFLOAD 1
using rsrc_t = __amdgpu_buffer_rsrc_t;
static __device__ __forceinline__ rsrc_t mkrsrc(const void* p) {
  return __builtin_amdgcn_make_buffer_rsrc((void*)p, (short)0, 0xFFFFFFFFu, 0x00020000);
}
static __device__ __forceinline__ v8h bload16(rsrc_t r, int byteOff) {
  union { u32x4 u; v8h h; } c;
  c.u = __builtin_amdgcn_raw_ptr_buffer_load_b128(r, byteOff, 0, 17);  // sc0|sc1
  return c.h;
}
#endif

static __device__ __forceinline__ void signalDone(unsigned* slots, int mySlot, unsigned val) {
  __builtin_amdgcn_s_waitcnt(0);
  __syncthreads();
  if (threadIdx.x == 0)
    __hip_atomic_store(&slots[(size_t)mySlot * 16], val, __ATOMIC_RELAXED, AGT);
}

static __device__ __forceinline__ void waitFor(unsigned* slots, int t0, int t1) {
  int tid = threadIdx.x;
  if (tid < 64) {
    int tgt = (tid < 32) ? t0 : t1;
    if (tgt > 0) {
      while ((int)__hip_atomic_load(&slots[(size_t)tid * 16],
                                    __ATOMIC_RELAXED, AGT) < tgt)
        __builtin_amdgcn_s_sleep(1);
    }
  }
  __syncthreads();
#if __has_builtin(__builtin_amdgcn_sched_barrier)
  __builtin_amdgcn_sched_barrier(0);
#endif
}

// Weight slice (64 gate-cols x K) fp32->fp16 into LDS, fragment order.
static __device__ __attribute__((noinline)) void loadWeights(
    int tid, int hc0, const float* W1, int ld1, int K1,
    const float* W2, int K) {
  extern __shared__ char smem[];
  int c = tid >> 2, sub = tid & 3;
  int nt = c >> 4, l = c & 15;
  int n = nt * HHD + hc0 + l;
  int Kq = K >> 2;
  for (int k = sub * Kq; k < (sub + 1) * Kq; ++k) {
    float v;
    if (k < K1) v = W1[(size_t)n * ld1 + k];
    else        v = W2[(size_t)n * HHD + (k - K1)];
    int kc = k >> 6, ks = (k >> 5) & 1, quad = (k >> 3) & 3, j = k & 7;
    int off = (((kc * 2 + ks) * 4 + nt) * 64 + quad * 16 + l) * 16 + j * 2;
    *(_Float16*)(smem + WOFF + off) = (_Float16)v;
  }
}

// One LSTM cell step. Waves partition M. A from swizzled global buffers:
// h via coalesced 16B bypass loads (base+lane*16), x via cached swizzled
// fp16 (read-only). B from LDS, conflict-free. fp32 acc in MFMA.
template <int NC>
static __device__ __attribute__((noinline)) void gemmStep(
    int tid, int m0, int hc0, const float* xstep, const char* xsT,
    const _Float16* src1, const _Float16* src2,
    int rank1, _Float16* hout, float* creg) {
  extern __shared__ char smem[];
  int lane = tid & 63, wave = tid >> 6;
  int l15 = lane & 15, quad = lane >> 4;

  v4f zero4 = {0.f, 0.f, 0.f, 0.f};
  v4f acc0 = zero4, acc1 = zero4, acc2 = zero4, acc3 = zero4;

  int rt = (m0 >> 4) + wave;               // row-tile in 256-row buffers
  int hBase = rt * 16384 + lane * 16;      // rt*8kc*2ks*1024
  const char* wb = smem + WOFF + (size_t)lane * 16;
  bool hasX = (xsT != nullptr) || (xstep != nullptr);

#if HAVE_BUFLOAD
  rsrc_t r1 = mkrsrc(src1);
  rsrc_t r2 = (src2 != nullptr) ? mkrsrc(src2) : r1;
#endif

#pragma unroll
  for (int ci = 0; ci < NC; ++ci) {
    v8h ak0, ak1;
    if (hasX && ci == 0) {
      if (xsT != nullptr) {
        const char* xb = xsT + rt * 2048 + lane * 16;
        ak0 = *(const v8h*)(xb);          // cached, coalesced, read-only
        ak1 = *(const v8h*)(xb + 1024);
      } else {
        int ra = m0 + wave * 16 + l15;    // fp32 fallback (scattered, cached)
        const float* xr = xstep + (size_t)ra * (TINN * FF) + quad * 8;
        v4f f00 = *(const v4f*)(xr);
        v4f f01 = *(const v4f*)(xr + 4);
        v4f f10 = *(const v4f*)(xr + 32);
        v4f f11 = *(const v4f*)(xr + 36);
#pragma unroll
        for (int e = 0; e < 4; ++e) {
          ak0[e] = (_Float16)f00[e]; ak0[4 + e] = (_Float16)f01[e];
          ak1[e] = (_Float16)f10[e]; ak1[4 + e] = (_Float16)f11[e];
        }
      }
    } else {
      int cj = hasX ? ci - 1 : ci;
      bool inS2 = (src2 != nullptr) && (cj >= 8);
      int kcL = inS2 ? cj - 8 : cj;
      int off = hBase + kcL * 2048;
#if HAVE_BUFLOAD
      ak0 = bload16(inS2 ? r2 : r1, off);
      ak1 = bload16(inS2 ? r2 : r1, off + 1024);
#else
      const _Float16* pr = (inS2 ? src2 : src1) + off / 2;
      ak0 = aload16(pr);
      ak1 = aload16(pr + 512);
#endif
    }
    const char* bb = wb + (size_t)ci * 8192;
#pragma unroll
    for (int ks = 0; ks < 2; ++ks) {
      v8h a = ks ? ak1 : ak0;
      v8h b0 = *(const v8h*)(bb + (ks * 4 + 0) * 1024);
      v8h b1 = *(const v8h*)(bb + (ks * 4 + 1) * 1024);
      v8h b2 = *(const v8h*)(bb + (ks * 4 + 2) * 1024);
      v8h b3 = *(const v8h*)(bb + (ks * 4 + 3) * 1024);
      acc0 = __builtin_amdgcn_mfma_f32_16x16x32_f16(a, b0, acc0, 0, 0, 0);
      acc1 = __builtin_amdgcn_mfma_f32_16x16x32_f16(a, b1, acc1, 0, 0, 0);
      acc2 = __builtin_amdgcn_mfma_f32_16x16x32_f16(a, b2, acc2, 0, 0, 0);
      acc3 = __builtin_amdgcn_mfma_f32_16x16x32_f16(a, b3, acc3, 0, 0, 0);
    }
  }

  float* gb = (float*)(smem + GBUF_OFF);
#pragma unroll
  for (int r = 0; r < 4; ++r) {
    int row = wave * 16 + quad * 4 + r;
    gb[row * 65 + l15] = acc0[r];
    gb[row * 65 + 16 + l15] = acc1[r];
    gb[row * 65 + 32 + l15] = acc2[r];
    gb[row * 65 + 48 + l15] = acc3[r];
  }
  __syncthreads();

  float* bias = (float*)(smem + BIAS_OFF);
  float* wih0 = (float*)(smem + WIH0_OFF);
  float* prevl = (float*)(smem + PREV_OFF);
  int m = tid >> 2, jb = (tid & 3) * 4;
  float pv = rank1 ? prevl[m] : 0.0f;
  v4h hh;
#pragma unroll
  for (int i = 0; i < 4; ++i) {
    int j = jb + i;
    float gi = gb[m * 65 + j] + bias[j];
    float gf = gb[m * 65 + 16 + j] + bias[16 + j];
    float gg = gb[m * 65 + 32 + j] + bias[32 + j];
    float go = gb[m * 65 + 48 + j] + bias[48 + j];
    if (rank1) {
      gi += pv * wih0[j]; gf += pv * wih0[16 + j];
      gg += pv * wih0[32 + j]; go += pv * wih0[48 + j];
    }
    float c = sigm(gf) * creg[i] + sigm(gi) * tanh_f(gg);
    float h = sigm(go) * tanh_f(c);
    creg[i] = c;
    hh[i] = (_Float16)h;
  }
  // swizzled h write: 4 consecutive j in one 8B slot
  {
    int mg = m0 + m;
    int c0 = hc0 + jb;
    int off = (((mg >> 4) * 8 + (c0 >> 6)) * 2 + ((c0 >> 5) & 1)) * 1024 +
              ((((c0 >> 3) & 3) * 16 + (mg & 15)) * 16) + (c0 & 7) * 2;
    astore8(hout + off / 2, hh);
  }
}

__global__ void __launch_bounds__(256, 1)
seq2seq_kernel(const float* x,
               const float* e0wi, const float* e0wh, const float* e0bi, const float* e0bh,
               const float* e1wi, const float* e1wh, const float* e1bi, const float* e1bh,
               const float* d0wi, const float* d0wh, const float* d0bi, const float* d0bh,
               const float* d1wi, const float* d1wh, const float* d1bi, const float* d1bh,
               const float* pw, const float* pb,
               float* out, char* ws, int useXs) {
  extern __shared__ char smem[];
  int tid = threadIdx.x, bid = blockIdx.x;
  int group = bid >> 6;
  int r = bid & 63;
  bool isL1 = (r >= 32);
  int hcTile = r & 31;
  int hc0 = hcTile * 16;
  int m0 = group * 64;
  unsigned* slots = (unsigned*)(ws + WS_BAR) + (size_t)group * 1024;
  int mySlot = isL1 ? 32 + hcTile : hcTile;
  char* xs = useXs ? (ws + WS_XS) : nullptr;

  _Float16* h0b[4]; _Float16* h1b[2];
  h0b[0] = (_Float16*)(ws + WS_HOFF);
  h0b[1] = (_Float16*)(ws + WS_HOFF + 1 * HBYTES);
  h0b[2] = (_Float16*)(ws + WS_HOFF + 2 * HBYTES);
  h0b[3] = (_Float16*)(ws + WS_HOFF + 3 * HBYTES);
  h1b[0] = (_Float16*)(ws + WS_HOFF + 4 * HBYTES);
  h1b[1] = (_Float16*)(ws + WS_HOFF + 5 * HBYTES);

  float creg[4];
  creg[0] = 0.f; creg[1] = 0.f; creg[2] = 0.f; creg[3] = 0.f;

  // zero the "step -1" buffers (h0[3], h1[1]) group slice (64KB each;
  // group slice = bytes [g*65536, (g+1)*65536) in swizzled layout too)
  {
    int t16 = r * 256 + tid;
    char* base = (t16 < 8192) ? (char*)h0b[3] : (char*)h1b[1];
    int idx = t16 & 8191;
    astore8z(base + (size_t)m0 * HHD * 2 + (size_t)idx * 8);
  }

  // one-time x -> xs transpose (fp32 -> fp16 swizzled), group-partitioned:
  // block r handles t = r + 64k. Gated by the init flags below.
  if (xs) {
    int m = m0 + (tid & 63);
    int cb = (tid >> 6) * 16;
    int rt = m >> 4, l15m = m & 15;
    for (int k = 0; k < 8; ++k) {
      int t = r + k * 64;
      const float* xp = x + (size_t)m * (TINN * FF) + (size_t)t * FF + cb;
      v4f f0 = *(const v4f*)(xp);
      v4f f1 = *(const v4f*)(xp + 4);
      v4f f2 = *(const v4f*)(xp + 8);
      v4f f3 = *(const v4f*)(xp + 12);
      v4h h0_, h1_, h2_, h3_;
#pragma unroll
      for (int e = 0; e < 4; ++e) {
        h0_[e] = (_Float16)f0[e]; h1_[e] = (_Float16)f1[e];
        h2_[e] = (_Float16)f2[e]; h3_[e] = (_Float16)f3[e];
      }
      char* xt = xs + (size_t)t * XS_TBYTES;
      v4h hs[4] = {h0_, h1_, h2_, h3_};
#pragma unroll
      for (int s = 0; s < 4; ++s) {
        int c0 = cb + 4 * s;
        int off = ((rt * 2 + ((c0 >> 5) & 1)) * 1024) +
                  ((((c0 >> 3) & 3) * 16 + l15m) * 16) + (c0 & 7) * 2;
        astore8((_Float16*)(xt + off), hs[s]);
      }
    }
  }

  if (!isL1) {
    loadWeights(tid, hc0, e0wi, 64, 64, e0wh, 576);
    if (tid < 64) {
      int n = (tid >> 4) * HHD + hc0 + (tid & 15);
      ((float*)(smem + BIAS_OFF))[tid] = e0bi[n] + e0bh[n];
    }
  } else {
    loadWeights(tid, hc0, e1wi, 512, 512, e1wh, 1024);
    if (tid < 64) {
      int n = (tid >> 4) * HHD + hc0 + (tid & 15);
      ((float*)(smem + BIAS_OFF))[tid] = e1bi[n] + e1bh[n];
    }
  }
  signalDone(slots, mySlot, 1);

  if (!isL1) {
    // ---------------- encoder layer 0 ----------------
    for (int p = 0; p < TINN; ++p) {
      waitFor(slots, p + 1, p - 2);
      gemmStep<9>(tid, m0, hc0, x + (size_t)p * FF,
                  xs ? xs + (size_t)p * XS_TBYTES : nullptr,
                  h0b[(p + 3) & 3], nullptr, 0, h0b[p & 3], creg);
      signalDone(slots, mySlot, p + 2);
    }
    // ---------------- decoder layer 0 ----------------
    loadWeights(tid, hc0, d0wh, 512, 512, nullptr, 512);
    if (tid < 64) {
      int n = (tid >> 4) * HHD + hc0 + (tid & 15);
      ((float*)(smem + BIAS_OFF))[tid] = d0bi[n] + d0bh[n];
      ((float*)(smem + WIH0_OFF))[tid] = d0wi[n];
    }
    for (int k = tid; k < 512; k += 256) ((float*)(smem + PROJW_OFF))[k] = pw[k];
    if (tid == 0) ((float*)(smem + PROJB_OFF))[0] = pb[0];
    for (int t = 0; t <= TOUTN; ++t) {
      int u = TINN + t;
      waitFor(slots, u + 1, u + 1);
      float* prevl = (float*)(smem + PREV_OFF);
      if (t == 0) {
        if (tid < 64)
          prevl[tid] = x[(size_t)(m0 + tid) * (TINN * FF) + 511 * 64 + 63];
      } else {
        // prev(t) = h1(t-1) . projW + proj_b  (swizzled h1 reads)
        float* part = (float*)(smem + PART_OFF);
        float* pjw = (float*)(smem + PROJW_OFF);
        const _Float16* h1base = h1b[(u + 1) & 1];
        int m = m0 + (tid >> 2);
        int rt = m >> 4, l15m = m & 15;
        int kc0 = (tid & 3) * 2;
        float s = 0.f;
#pragma unroll
        for (int kc = kc0; kc < kc0 + 2; ++kc)
#pragma unroll
          for (int ks = 0; ks < 2; ++ks)
#pragma unroll
            for (int q = 0; q < 4; ++q) {
              int off = ((rt * 8 + kc) * 2 + ks) * 1024 + ((q * 16 + l15m) * 16);
              v8h hv = aload16(h1base + off / 2);
              const float* w = pjw + kc * 64 + ks * 32 + q * 8;
#pragma unroll
              for (int e = 0; e < 8; ++e) s += (float)hv[e] * w[e];
            }
        part[tid] = s;
        __syncthreads();
        if (tid < 64) {
          float p4 = part[tid * 4] + part[tid * 4 + 1] + part[tid * 4 + 2] +
                     part[tid * 4 + 3] + ((float*)(smem + PROJB_OFF))[0];
          prevl[tid] = p4;
          if (hcTile == 0) out[(size_t)(m0 + tid) * TOUTN + (t - 1)] = p4;
        }
      }
      __syncthreads();
      if (t < TOUTN) {
        gemmStep<8>(tid, m0, hc0, nullptr, nullptr, h0b[(u + 3) & 3], nullptr,
                    1, h0b[u & 3], creg);
        signalDone(slots, mySlot, u + 2);
      }
    }
  } else {
    // ---------------- encoder layer 1 ----------------
    for (int s = 0; s < TINN; ++s) {
      waitFor(slots, s + 2, s + 1);
      gemmStep<16>(tid, m0, hc0, nullptr, nullptr, h0b[s & 3], h1b[(s + 1) & 1],
                   0, h1b[s & 1], creg);
      signalDone(slots, mySlot, s + 2);
    }
    // ---------------- decoder layer 1 ----------------
    loadWeights(tid, hc0, d1wi, 512, 512, d1wh, 1024);
    if (tid < 64) {
      int n = (tid >> 4) * HHD + hc0 + (tid & 15);
      ((float*)(smem + BIAS_OFF))[tid] = d1bi[n] + d1bh[n];
    }
    for (int t = 0; t < TOUTN; ++t) {
      int u = TINN + t;
      waitFor(slots, u + 2, u + 1);
      gemmStep<16>(tid, m0, hc0, nullptr, nullptr, h0b[u & 3], h1b[(u + 1) & 1],
                   0, h1b[u & 1], creg);
      signalDone(slots, mySlot, u + 2);
    }
  }
}

extern "C" void kernel_launch(void* const* d_in, const int* in_sizes, int n_in,
                              void* d_out, int out_size, void* d_ws, size_t ws_size,
                              hipStream_t stream) {
  const float* x = (const float*)d_in[0];
  const float* e0wi = (const float*)d_in[2];
  const float* e0wh = (const float*)d_in[3];
  const float* e0bi = (const float*)d_in[4];
  const float* e0bh = (const float*)d_in[5];
  const float* e1wi = (const float*)d_in[6];
  const float* e1wh = (const float*)d_in[7];
  const float* e1bi = (const float*)d_in[8];
  const float* e1bh = (const float*)d_in[9];
  const float* d0wi = (const float*)d_in[10];
  const float* d0wh = (const float*)d_in[11];
  const float* d0bi = (const float*)d_in[12];
  const float* d0bh = (const float*)d_in[13];
  const float* d1wi = (const float*)d_in[14];
  const float* d1wh = (const float*)d_in[15];
  const float* d1bi = (const float*)d_in[16];
  const float* d1bh = (const float*)d_in[17];
  const float* pw = (const float*)d_in[18];
  const float* pb = (const float*)d_in[19];

  int useXs = (ws_size >= WS_NEED) ? 1 : 0;
  (void)hipFuncSetAttribute((const void*)seq2seq_kernel,
                            hipFuncAttributeMaxDynamicSharedMemorySize, SMEM_TOTAL);
  (void)hipMemsetAsync(d_ws, 0, 16384, stream);  // progress slots
  seq2seq_kernel<<<dim3(256), dim3(256), SMEM_TOTAL, stream>>>(
      x, e0wi, e0wh, e0bi, e0bh, e1wi, e1wh, e1bi, e1bh,
      d0wi, d0wh, d0bi, d0bh, d1wi, d1wh, d1bi, d1bh,
      pw, pb, (float*)d_out, (char*)d_ws, useXs);
}